// Round 1
// baseline (351.222 us; speedup 1.0000x reference)
//
#include <hip/hip_runtime.h>

// Layer_Hist: per-row 30-bin histogram of x[4096, 16384] fp32.
//   k = clip(floor((x - LO)/W), -1, 28) + 1 ;  W = 12/28
//   out column order: [bin0, bin29, bin1..bin28]
//
// Strategy: 1 block / row, 256 threads, float4 coalesced loads.
// Per-thread privatized LDS histograms (stride 33 dwords -> bank = (t+bin)%32,
// worst-case free 2-way aliasing), ds_add_u32 no-return increments (no
// contention: each thread owns its slots). Two-stage reduction, reorder, store.

#define NBINS   30
#define STRIDE  33        // per-thread LDS stride in dwords (conflict-light)
#define THREADS 256
#define ROWLEN  16384
#define ITERS   (ROWLEN / 4 / THREADS)   // 16 float4 loads per thread

__global__ __launch_bounds__(THREADS, 4) void hist_kernel(
    const float* __restrict__ x, float* __restrict__ out)
{
    __shared__ unsigned int h[THREADS * STRIDE];   // 33792 B
    __shared__ unsigned int partial[8 * NBINS];    //   960 B

    const int t   = threadIdx.x;
    const int row = blockIdx.x;

    unsigned int* hp = &h[t * STRIDE];
#pragma unroll
    for (int i = 0; i < STRIDE; ++i) hp[i] = 0u;
    __syncthreads();

    // W and invW constant-folded at compile time with correct fp32 rounding.
    const float W    = (float)(12.0 / 28.0);       // 0.42857143f
    const float invW = 1.0f / W;

    const float4* xr = (const float4*)(x + (size_t)row * ROWLEN);

#pragma unroll
    for (int i = 0; i < ITERS; ++i) {
        float4 v = xr[t + i * THREADS];
        {
            int k = __float2int_rd((v.x + 6.0f) * invW);
            k = min(max(k, -1), NBINS - 2) + 1;
            atomicAdd(&hp[k], 1u);
        }
        {
            int k = __float2int_rd((v.y + 6.0f) * invW);
            k = min(max(k, -1), NBINS - 2) + 1;
            atomicAdd(&hp[k], 1u);
        }
        {
            int k = __float2int_rd((v.z + 6.0f) * invW);
            k = min(max(k, -1), NBINS - 2) + 1;
            atomicAdd(&hp[k], 1u);
        }
        {
            int k = __float2int_rd((v.w + 6.0f) * invW);
            k = min(max(k, -1), NBINS - 2) + 1;
            atomicAdd(&hp[k], 1u);
        }
    }
    __syncthreads();

    // Stage 1: 240 threads = 30 bins x 8 groups; group g sums 32 copies.
    if (t < 240) {
        const int bin = t % NBINS;
        const int g   = t / NBINS;
        unsigned int s = 0;
        const int c0 = g * 32;
#pragma unroll
        for (int c = 0; c < 32; ++c)
            s += h[(c0 + c) * STRIDE + bin];
        partial[g * NBINS + bin] = s;
    }
    __syncthreads();

    // Stage 2: 30 threads sum 8 partials, reorder, store.
    if (t < NBINS) {
        unsigned int s = 0;
#pragma unroll
        for (int g = 0; g < 8; ++g) s += partial[g * NBINS + t];
        const int dst = (t == 0) ? 0 : (t == NBINS - 1) ? 1 : (t + 1);
        out[(size_t)row * NBINS + dst] = (float)s;
    }
}

extern "C" void kernel_launch(void* const* d_in, const int* in_sizes, int n_in,
                              void* d_out, int out_size, void* d_ws, size_t ws_size,
                              hipStream_t stream)
{
    const float* x  = (const float*)d_in[0];
    float* out      = (float*)d_out;
    const int rows  = in_sizes[0] / ROWLEN;   // 4096
    hist_kernel<<<rows, THREADS, 0, stream>>>(x, out);
}

// Round 3
// 334.559 us; speedup vs baseline: 1.0498x; 1.0498x over previous
//
#include <hip/hip_runtime.h>

// Layer_Hist: per-row 30-bin histogram of x[4096, 16384] fp32.
//   k = clip(floor((x - LO)/W), -1, 28) + 1 ;  W = 12/28
//   out column order: [bin0, bin29, bin1..bin28]
//
// R3: same as R2 (transposed privatized LDS layout h[bin*256 + t] -> ds_add
// bank = t%32, data-independent, free 2-way), but the nontemporal load goes
// through a native clang ext_vector float4 (HIP_vector_type is a struct and
// __builtin_nontemporal_load rejects it).

#define NBINS   30
#define THREADS 256
#define ROWLEN  16384
#define ITERS   (ROWLEN / 4 / THREADS)   // 16 float4 loads per thread

typedef float f4 __attribute__((ext_vector_type(4)));

__global__ __launch_bounds__(THREADS, 4) void hist_kernel(
    const float* __restrict__ x, float* __restrict__ out)
{
    __shared__ unsigned int h[NBINS * THREADS];   // 30720 B, bank = t%32
    __shared__ unsigned int partial[8 * NBINS];   //   960 B

    const int t   = threadIdx.x;
    const int row = blockIdx.x;

    // zero own column: bank = t%32 for every write (2-way free)
#pragma unroll
    for (int b = 0; b < NBINS; ++b) h[b * THREADS + t] = 0u;
    __syncthreads();

    const float W    = (float)(12.0 / 28.0);
    const float invW = 1.0f / W;            // 2.3333333f
    const float c6   = 6.0f * invW;         // folded (x+6)*invW = x*invW + c6

    const f4* xr = (const f4*)(x + (size_t)row * ROWLEN);
    // bin = k+1 folded into base: index = (k+1)*256 + t
    const int base = THREADS + t;

#pragma unroll
    for (int i = 0; i < ITERS; ++i) {
        f4 v = __builtin_nontemporal_load(&xr[t + i * THREADS]);
        {
            int k = __float2int_rd(fmaf(v.x, invW, c6));
            k = min(max(k, -1), NBINS - 2);
            atomicAdd(&h[k * THREADS + base], 1u);
        }
        {
            int k = __float2int_rd(fmaf(v.y, invW, c6));
            k = min(max(k, -1), NBINS - 2);
            atomicAdd(&h[k * THREADS + base], 1u);
        }
        {
            int k = __float2int_rd(fmaf(v.z, invW, c6));
            k = min(max(k, -1), NBINS - 2);
            atomicAdd(&h[k * THREADS + base], 1u);
        }
        {
            int k = __float2int_rd(fmaf(v.w, invW, c6));
            k = min(max(k, -1), NBINS - 2);
            atomicAdd(&h[k * THREADS + base], 1u);
        }
    }
    __syncthreads();

    // Stage 1: 240 threads = 30 bins x 8 groups of 32 columns.
    // Rotate start by `b` so lanes spread across banks (else all lanes read
    // bank i%32 simultaneously -> 64-way conflict).
    if (t < 240) {
        const int b = t % NBINS;
        const int g = t / NBINS;
        unsigned int s = 0;
#pragma unroll
        for (int i = 0; i < 32; ++i)
            s += h[b * THREADS + g * 32 + ((i + b) & 31)];
        partial[g * NBINS + b] = s;
    }
    __syncthreads();

    // Stage 2: 30 threads sum 8 partials, reorder, store.
    if (t < NBINS) {
        unsigned int s = 0;
#pragma unroll
        for (int g = 0; g < 8; ++g) s += partial[g * NBINS + t];
        const int dst = (t == 0) ? 0 : (t == NBINS - 1) ? 1 : (t + 1);
        out[(size_t)row * NBINS + dst] = (float)s;
    }
}

extern "C" void kernel_launch(void* const* d_in, const int* in_sizes, int n_in,
                              void* d_out, int out_size, void* d_ws, size_t ws_size,
                              hipStream_t stream)
{
    const float* x  = (const float*)d_in[0];
    float* out      = (float*)d_out;
    const int rows  = in_sizes[0] / ROWLEN;   // 4096
    hist_kernel<<<rows, THREADS, 0, stream>>>(x, out);
}

// Round 4
// 327.303 us; speedup vs baseline: 1.0731x; 1.0222x over previous
//
#include <hip/hip_runtime.h>

// Layer_Hist: per-row 30-bin histogram of x[4096, 16384] fp32.
//   bin = clip(floor((x-LO)/W), -1, 28) + 1  ==  floor(clamp(x*invW + 15, 0, 29))
//   out column order: [bin0, bin29, bin1..bin28]
//
// R4: anti-spill restructure. R1/R3 both sat at ~340 us regardless of LDS
// layout -> bottleneck was never LDS banks. Theory: __launch_bounds__(256,4)'s
// 128-VGPR cap + full 16x unroll (64 VGPRs of float4 in flight) forced scratch
// spills (global-memory round trip per element). Fix:
//   - no min-waves cap (occupancy is LDS-limited: 31.7 KB -> 5 blocks/CU)
//   - explicit 2-stage software pipeline: 4 groups of 4 float4, prefetch
//     next group while processing current (<=8 float4 = 32 VGPRs in flight)
//   - per-element cost: v_fma, v_med3_f32, v_cvt_flr_i32, v_lshl_add, ds_add
// LDS layout stays transposed (h[bin*256+t], bank = t%32, data-independent,
// free 2-way). Private counters -> no-return ds_add_u32, no contention.

#define NBINS   30
#define THREADS 256
#define ROWLEN  16384
#define VPG     4                       // float4 per group per thread
#define GROUPS  (ROWLEN / 4 / THREADS / VPG)   // 4 groups

typedef float f4 __attribute__((ext_vector_type(4)));

__global__ __launch_bounds__(THREADS) void hist_kernel(
    const float* __restrict__ x, float* __restrict__ out)
{
    __shared__ unsigned int h[NBINS * THREADS];   // 30720 B
    __shared__ unsigned int partial[8 * NBINS];   //   960 B

    const int t   = threadIdx.x;
    const int row = blockIdx.x;

#pragma unroll
    for (int b = 0; b < NBINS; ++b) h[b * THREADS + t] = 0u;
    __syncthreads();

    const float invW = 28.0f / 12.0f;   // 2.3333333f
    const float c15  = 15.0f;           // 6*invW + 1 (bin offset folded in)

    const f4* xr = (const f4*)(x + (size_t)row * ROWLEN);

    f4 cur[VPG], nxt[VPG];
#pragma unroll
    for (int j = 0; j < VPG; ++j)
        cur[j] = __builtin_nontemporal_load(&xr[t + j * THREADS]);

#pragma unroll 1
    for (int g = 0; g < GROUPS; ++g) {
        if (g + 1 < GROUPS) {
#pragma unroll
            for (int j = 0; j < VPG; ++j)
                nxt[j] = __builtin_nontemporal_load(
                    &xr[t + ((g + 1) * VPG + j) * THREADS]);
        }
#pragma unroll
        for (int j = 0; j < VPG; ++j) {
            f4 v = cur[j];
#pragma unroll
            for (int c = 0; c < 4; ++c) {
                float f = fmaf(v[c], invW, c15);
                f = fminf(fmaxf(f, 0.0f), 29.0f);       // v_med3_f32
                int bin = __float2int_rd(f);            // v_cvt_flr_i32_f32
                atomicAdd(&h[bin * THREADS + t], 1u);   // ds_add_u32 (no rtn)
            }
        }
#pragma unroll
        for (int j = 0; j < VPG; ++j) cur[j] = nxt[j];
    }
    __syncthreads();

    // Stage 1: 240 threads = 30 bins x 8 groups of 32 columns, rotated reads.
    if (t < 240) {
        const int b = t % NBINS;
        const int g = t / NBINS;
        unsigned int s = 0;
#pragma unroll
        for (int i = 0; i < 32; ++i)
            s += h[b * THREADS + g * 32 + ((i + b) & 31)];
        partial[g * NBINS + b] = s;
    }
    __syncthreads();

    // Stage 2: 30 threads sum 8 partials, reorder, store.
    if (t < NBINS) {
        unsigned int s = 0;
#pragma unroll
        for (int g = 0; g < 8; ++g) s += partial[g * NBINS + t];
        const int dst = (t == 0) ? 0 : (t == NBINS - 1) ? 1 : (t + 1);
        out[(size_t)row * NBINS + dst] = (float)s;
    }
}

extern "C" void kernel_launch(void* const* d_in, const int* in_sizes, int n_in,
                              void* d_out, int out_size, void* d_ws, size_t ws_size,
                              hipStream_t stream)
{
    const float* x  = (const float*)d_in[0];
    float* out      = (float*)d_out;
    const int rows  = in_sizes[0] / ROWLEN;   // 4096
    hist_kernel<<<rows, THREADS, 0, stream>>>(x, out);
}